// Round 2
// baseline (97.526 us; speedup 1.0000x reference)
//
#include <hip/hip_runtime.h>
#include <stdint.h>

#define NTOK 8192
#define NCOL 4096     // DIM == VOCAB
#define RANK 256
#define TPB  64       // tokens per block
#define CPB  512      // cols per block
#define NWAVE 4

typedef __attribute__((ext_vector_type(8))) short bf16x8;
typedef __attribute__((ext_vector_type(4))) float f32x4;

__device__ __forceinline__ unsigned short f2bf(float f) {
    unsigned int u = __float_as_uint(f);
    u += 0x7fffu + ((u >> 16) & 1u);   // RNE
    return (unsigned short)(u >> 16);
}

// ---- pre-pass 1: A fp32 [4096][256] -> bf16 row-major ----
__global__ __launch_bounds__(256) void cast_A_kernel(
    const float* __restrict__ A, unsigned short* __restrict__ Abf)
{
    int i = blockIdx.x * 256 + threadIdx.x;          // 262144 threads, 4 elems each
    float4 v = reinterpret_cast<const float4*>(A)[i];
    ushort4 o;
    o.x = f2bf(v.x); o.y = f2bf(v.y); o.z = f2bf(v.z); o.w = f2bf(v.w);
    reinterpret_cast<ushort4*>(Abf)[i] = o;
}

// ---- pre-pass 2: B fp32 [256][4096] -> bf16 MFMA-B-fragment order ----
// frag layout: flat uint4 index = (ct*8 + ks)*64 + lane, holding 8 bf16:
//   element j = B[ks*32 + (lane>>4)*8 + j][ct*16 + (lane&15)]
__global__ __launch_bounds__(256) void swizzle_B_kernel(
    const float* __restrict__ B, unsigned short* __restrict__ Bfrag)
{
    int gt = blockIdx.x * 256 + threadIdx.x;         // 131072 threads
    int ct = gt >> 9;
    int rem = gt & 511;
    int ks = rem >> 6;
    int ln = rem & 63;
    int col = ct * 16 + (ln & 15);
    int kb  = ks * 32 + ((ln >> 4) << 3);
    unsigned short pk[8];
    #pragma unroll
    for (int j = 0; j < 8; ++j)
        pk[j] = f2bf(B[(size_t)(kb + j) * NCOL + col]);
    uint4 o;
    o.x = (unsigned)pk[0] | ((unsigned)pk[1] << 16);
    o.y = (unsigned)pk[2] | ((unsigned)pk[3] << 16);
    o.z = (unsigned)pk[4] | ((unsigned)pk[5] << 16);
    o.w = (unsigned)pk[6] | ((unsigned)pk[7] << 16);
    reinterpret_cast<uint4*>(Bfrag)[gt] = o;
}

// ---- main: fused gather + LoRA GEMM + W add + mask ----
__global__ __launch_bounds__(256) void emb_lora_mfma(
    const int* __restrict__ x,
    const int* __restrict__ mask,
    const float* __restrict__ W,
    const unsigned short* __restrict__ Abf,
    const unsigned short* __restrict__ Bfrag,
    float* __restrict__ out)
{
    __shared__ unsigned short a_lds[TPB * RANK];     // 32 KB bf16
    __shared__ int s_idx[TPB];
    __shared__ int s_msk[TPB];

    const int tid  = threadIdx.x;
    const int lane = tid & 63;
    const int wave = tid >> 6;
    const int tok0 = blockIdx.x * TPB;
    const int col0 = blockIdx.y * CPB;

    if (tid < TPB) {
        s_idx[tid] = x[tok0 + tid];
        s_msk[tid] = mask[tok0 + tid];
    }
    __syncthreads();

    // stage 64 gathered A rows (bf16) into LDS: 2048 16B chunks, 8 per thread
    #pragma unroll
    for (int it = 0; it < 8; ++it) {
        int c = it * 256 + tid;
        int row = c >> 5;                 // 32 chunks per 512B row
        int off = (c & 31) << 3;          // elem offset within row
        uint4 v = *reinterpret_cast<const uint4*>(
            Abf + (size_t)s_idx[row] * RANK + off);
        *reinterpret_cast<uint4*>(a_lds + row * RANK + off) = v;
    }
    __syncthreads();

    // per-wave A fragments: wave owns tokens [wave*16, wave*16+16)
    const int arow = wave * 16 + (lane & 15);
    const unsigned short* ap = a_lds + arow * RANK + ((lane >> 4) << 3);
    bf16x8 afrag[8];
    #pragma unroll
    for (int s = 0; s < 8; ++s)
        afrag[s] = *reinterpret_cast<const bf16x8*>(ap + s * 32);

    const uint4* bbase = reinterpret_cast<const uint4*>(Bfrag);

    // 32 col-tiles of 16 cols each; all 4 waves share the B-frag stream (L1 hits)
    for (int t = 0; t < 32; ++t) {
        const int ct = blockIdx.y * 32 + t;
        const uint4* bq = bbase + (size_t)ct * 8 * 64 + lane;
        f32x4 acc = {0.f, 0.f, 0.f, 0.f};
        #pragma unroll
        for (int s = 0; s < 8; ++s) {
            uint4 braw = bq[s * 64];
            bf16x8 bfr = __builtin_bit_cast(bf16x8, braw);
            acc = __builtin_amdgcn_mfma_f32_16x16x32_bf16(afrag[s], bfr, acc, 0, 0, 0);
        }
        // epilogue: C/D layout col=lane&15, row=(lane>>4)*4+r
        const int col = col0 + t * 16 + (lane & 15);
        #pragma unroll
        for (int r = 0; r < 4; ++r) {
            const int row = wave * 16 + ((lane >> 4) << 2) + r;  // token in block
            float v = 0.f;
            if (!s_msk[row])
                v = acc[r] + W[(size_t)s_idx[row] * NCOL + col];
            out[(size_t)(tok0 + row) * NCOL + col] = v;
        }
    }
}

extern "C" void kernel_launch(void* const* d_in, const int* in_sizes, int n_in,
                              void* d_out, int out_size, void* d_ws, size_t ws_size,
                              hipStream_t stream) {
    (void)in_sizes; (void)n_in; (void)out_size; (void)ws_size;

    const int*   x    = (const int*)d_in[0];
    const int*   mask = (const int*)d_in[1];
    const float* W    = (const float*)d_in[2];
    const float* A    = (const float*)d_in[3];
    const float* B    = (const float*)d_in[4];
    float*       out  = (float*)d_out;

    unsigned short* Abf   = (unsigned short*)d_ws;                       // 2 MiB
    unsigned short* Bfrag = (unsigned short*)((char*)d_ws + (2u << 20)); // 2 MiB

    cast_A_kernel<<<dim3(NCOL * RANK / 4 / 256), dim3(256), 0, stream>>>(A, Abf);
    swizzle_B_kernel<<<dim3(RANK * NCOL / 8 / 256), dim3(256), 0, stream>>>(B, Bfrag);

    dim3 grid(NTOK / TPB, NCOL / CPB);   // (128, 8) = 1024 blocks
    emb_lora_mfma<<<grid, dim3(256), 0, stream>>>(x, mask, W, Abf, Bfrag, out);
}